// Round 10
// baseline (35.611 us; speedup 1.0000x reference)
//
#include <hip/hip_runtime.h>
#include <math.h>

// Problem constants
#define NB 8
#define NN 128
static constexpr float NEGV = -1000000.0f;

// Kernel 1: one workgroup per (b, r, s-half). 256 threads = 4 waves.
// R2/R9 load pattern preserved: 16 individually named float4/thread, all
// issued upfront, 1 KiB per wave-instruction. Local (per-half) softmax with
// (m, l) saved to ws; unnormalized per-e partial aggregation saved to ws.
// lane l: e = l>>5, c4 = l&31. Wave w (0..3) owns s_loc = w + 4*si, si=0..15.
__global__ __launch_bounds__(256)
void edge_attn_partial(const float* __restrict__ edge_msgs,
                       const float* __restrict__ node_states,
                       const float* __restrict__ W,
                       const float* __restrict__ bvec,
                       const int*   __restrict__ edges,
                       float* __restrict__ pout,   // [half][b][r][e][h][c]
                       float* __restrict__ mlm,    // [half][b][r][e][h] max
                       float* __restrict__ mll) {  // [half][b][r][e][h] sum
    const int blk  = blockIdx.x;
    const int r    = blk & 127;
    const int half = (blk >> 7) & 1;
    const int b    = blk >> 8;

    const int t  = threadIdx.x;
    const int w  = t >> 6;      // wave 0..3
    const int l  = t & 63;
    const int e  = l >> 5;      // 0/1
    const int c4 = l & 31;

    __shared__ float part[64 * 68];          // quad-partials [s_loc][e*32+h*8+g]
    __shared__ float wts [2 * 64 * 5];       // [e*320 + s_loc*5 + h] exp weights
    __shared__ float ebias[64 * 2];          // [s_loc*2 + e]
    __shared__ float nodep[4];
    __shared__ float outbuf[4][2][4][128];   // [wave][e][h][c]

    // ---- W_msg fragment for this lane's c-chunk
    float4 wm0 = *(const float4*)(W +   0 + c4 * 4);
    float4 wm1 = *(const float4*)(W + 256 + c4 * 4);
    float4 wm2 = *(const float4*)(W + 512 + c4 * 4);
    float4 wm3 = *(const float4*)(W + 768 + c4 * 4);

    // ---- stream base: this (b, r, half). per-s stride = 32768 floats
    const float* bp = edge_msgs
        + (size_t)b * (NN * NN * 256)
        + (size_t)(half * 64) * 32768
        + (size_t)r * 256
        + e * 128 + c4 * 4;

    float4 V0, V1, V2, V3, V4, V5, V6, V7, V8, V9, V10, V11, V12, V13, V14, V15;

#define LOADV(i) V##i = *(const float4*)(bp + (size_t)(w + 4 * (i)) * 32768);
    LOADV(0)  LOADV(1)  LOADV(2)  LOADV(3)
    LOADV(4)  LOADV(5)  LOADV(6)  LOADV(7)
    LOADV(8)  LOADV(9)  LOADV(10) LOADV(11)
    LOADV(12) LOADV(13) LOADV(14) LOADV(15)
#undef LOADV

    // ---- node projection: wave 0 only, 64-lane reduce (overlaps loads)
    if (w == 0) {
        float2 nv  = *(const float2*)(node_states + ((size_t)b * NN + r) * 128 + l * 2);
        float2 wn0 = *(const float2*)(W + 128 + l * 2);
        float2 wn1 = *(const float2*)(W + 384 + l * 2);
        float2 wn2 = *(const float2*)(W + 640 + l * 2);
        float2 wn3 = *(const float2*)(W + 896 + l * 2);
        float np0 = nv.x * wn0.x + nv.y * wn0.y;
        float np1 = nv.x * wn1.x + nv.y * wn1.y;
        float np2 = nv.x * wn2.x + nv.y * wn2.y;
        float np3 = nv.x * wn3.x + nv.y * wn3.y;
        #pragma unroll
        for (int m = 32; m >= 1; m >>= 1) {
            np0 += __shfl_xor(np0, m);
            np1 += __shfl_xor(np1, m);
            np2 += __shfl_xor(np2, m);
            np3 += __shfl_xor(np3, m);
        }
        if (l == 0) { nodep[0] = np0; nodep[1] = np1; nodep[2] = np2; nodep[3] = np3; }
    }

    // ---- edge mask bias for this half: 128 threads, one int each
    if (t < 128) {
        int s_loc = t >> 1;
        int ec    = t & 1;
        int s     = half * 64 + s_loc;
        int ev = edges[(((size_t)b * NN + s) * NN + r) * 3 + 1 + ec];
        ebias[s_loc * 2 + ec] = (1.0f - (float)ev) * NEGV;
    }

    // ---- Pass A: quad-partial scores (3 shuffles + 1 LDS store per si)
    const int hsel = l & 3;
    const int g    = (l >> 2) & 7;
    const bool o1  = (l & 1) != 0;
    const bool o2  = (l & 2) != 0;

#define SCOREV(d, si) {                                                        \
    float p0 = d.x * wm0.x + d.y * wm0.y + d.z * wm0.z + d.w * wm0.w;          \
    float p1 = d.x * wm1.x + d.y * wm1.y + d.z * wm1.z + d.w * wm1.w;          \
    float p2 = d.x * wm2.x + d.y * wm2.y + d.z * wm2.z + d.w * wm2.w;          \
    float p3 = d.x * wm3.x + d.y * wm3.y + d.z * wm3.z + d.w * wm3.w;          \
    float x01 = o1 ? p1 : p0, y01 = o1 ? p0 : p1;                              \
    float x23 = o1 ? p3 : p2, y23 = o1 ? p2 : p3;                              \
    float r01 = x01 + __shfl_xor(y01, 1);                                      \
    float r23 = x23 + __shfl_xor(y23, 1);                                      \
    float x2 = o2 ? r23 : r01, y2 = o2 ? r01 : r23;                            \
    float val = x2 + __shfl_xor(y2, 2);                                        \
    part[(w + 4 * (si)) * 68 + e * 32 + hsel * 8 + g] = val;                   \
}
    SCOREV(V0, 0)   SCOREV(V1, 1)   SCOREV(V2, 2)   SCOREV(V3, 3)
    SCOREV(V4, 4)   SCOREV(V5, 5)   SCOREV(V6, 6)   SCOREV(V7, 7)
    SCOREV(V8, 8)   SCOREV(V9, 9)   SCOREV(V10, 10) SCOREV(V11, 11)
    SCOREV(V12, 12) SCOREV(V13, 13) SCOREV(V14, 14) SCOREV(V15, 15)
#undef SCOREV
    __syncthreads();

    // ---- Local softmax over this half's 64 s per (e,h): 8 groups x 32 lanes
    {
        int p  = t >> 5;        // 0..7
        int j  = t & 31;
        int es = p & 1;
        int h  = p >> 1;
        float bb = bvec[h] + nodep[h];
        float y0, y1;
        #define SCORE(k, dst)                                                  \
        {                                                                      \
            int s_loc = j + 32 * k;                                            \
            const float* q = &part[s_loc * 68 + es * 32 + h * 8];              \
            float4 qa = *(const float4*)q;                                     \
            float4 qb = *(const float4*)(q + 4);                               \
            float x = (qa.x + qa.y + qa.z + qa.w)                              \
                    + (qb.x + qb.y + qb.z + qb.w) + bb;                        \
            x = x > 0.f ? x : expm1f(x);                                       \
            dst = x + ebias[s_loc * 2 + es];                                   \
        }
        SCORE(0, y0) SCORE(1, y1)
        #undef SCORE
        float m2 = fmaxf(y0, y1);
        #pragma unroll
        for (int m = 16; m >= 1; m >>= 1) m2 = fmaxf(m2, __shfl_xor(m2, m));
        float p0 = __expf(y0 - m2);
        float p1 = __expf(y1 - m2);
        float ls = p0 + p1;
        #pragma unroll
        for (int m = 16; m >= 1; m >>= 1) ls += __shfl_xor(ls, m);
        wts[es * 320 + (j +  0) * 5 + h] = p0;
        wts[es * 320 + (j + 32) * 5 + h] = p1;
        if (j == 0) {
            size_t mli = ((((size_t)half * NB + b) * NN + r) * 2 + es) * 4 + h;
            mlm[mli] = m2;
            mll[mli] = ls;
        }
    }
    __syncthreads();

    // ---- Pass B: unnormalized weighted aggregation (per e, no fold)
    float4 a0 = {0,0,0,0}, a1 = {0,0,0,0}, a2 = {0,0,0,0}, a3 = {0,0,0,0};
#define AGGV(d, si) {                                                          \
    int s_loc = w + 4 * (si);                                                  \
    float w0 = wts[e * 320 + s_loc * 5 + 0];                                   \
    float w1 = wts[e * 320 + s_loc * 5 + 1];                                   \
    float w2 = wts[e * 320 + s_loc * 5 + 2];                                   \
    float w3 = wts[e * 320 + s_loc * 5 + 3];                                   \
    a0.x += w0 * d.x; a0.y += w0 * d.y; a0.z += w0 * d.z; a0.w += w0 * d.w;    \
    a1.x += w1 * d.x; a1.y += w1 * d.y; a1.z += w1 * d.z; a1.w += w1 * d.w;    \
    a2.x += w2 * d.x; a2.y += w2 * d.y; a2.z += w2 * d.z; a2.w += w2 * d.w;    \
    a3.x += w3 * d.x; a3.y += w3 * d.y; a3.z += w3 * d.z; a3.w += w3 * d.w;    \
}
    AGGV(V0, 0)   AGGV(V1, 1)   AGGV(V2, 2)   AGGV(V3, 3)
    AGGV(V4, 4)   AGGV(V5, 5)   AGGV(V6, 6)   AGGV(V7, 7)
    AGGV(V8, 8)   AGGV(V9, 9)   AGGV(V10, 10) AGGV(V11, 11)
    AGGV(V12, 12) AGGV(V13, 13) AGGV(V14, 14) AGGV(V15, 15)
#undef AGGV

    *(float4*)&outbuf[w][e][0][c4 * 4] = a0;
    *(float4*)&outbuf[w][e][1][c4 * 4] = a1;
    *(float4*)&outbuf[w][e][2][c4 * 4] = a2;
    *(float4*)&outbuf[w][e][3][c4 * 4] = a3;
    __syncthreads();

    // ---- cross-wave reduce + store partial: 1024 floats (e,h,c), 4/thread
    #pragma unroll
    for (int k = 0; k < 4; ++k) {
        int idx = t + 256 * k;          // ee*512 + hh*128 + cc
        int ee = idx >> 9;
        int hh = (idx >> 7) & 3;
        int cc = idx & 127;
        float sv = outbuf[0][ee][hh][cc] + outbuf[1][ee][hh][cc]
                 + outbuf[2][ee][hh][cc] + outbuf[3][ee][hh][cc];
        size_t po = (((((size_t)half * NB + b) * NN + r) * 2 + ee) * 4 + hh) * 128 + cc;
        pout[po] = sv;
    }
}

// Kernel 2: merge halves (two-level softmax) and fold e.
// out[b,r,h,c] = sum_e (acc0*exp(m0-M) + acc1*exp(m1-M)) / (l0*exp(m0-M)+l1*exp(m1-M))
__global__ __launch_bounds__(256)
void edge_attn_combine(const float* __restrict__ pout,
                       const float* __restrict__ mlm,
                       const float* __restrict__ mll,
                       float* __restrict__ out) {
    int i = blockIdx.x * 256 + threadIdx.x;   // float4 index, 131072 total
    int c4 = i & 31;
    int h  = (i >> 5) & 3;
    int r  = (i >> 7) & 127;
    int b  = i >> 14;

    const float4* p4 = (const float4*)pout;
    float4 res = {0, 0, 0, 0};
    #pragma unroll
    for (int e = 0; e < 2; ++e) {
        size_t idx0 = ((((size_t)0 * NB + b) * NN + r) * 2 + e) * 4 + h;
        size_t idx1 = idx0 + (size_t)NB * NN * 2 * 4;
        float m0 = mlm[idx0], m1 = mlm[idx1];
        float l0 = mll[idx0], l1 = mll[idx1];
        float M  = fmaxf(m0, m1);
        float w0 = __expf(m0 - M);
        float w1 = __expf(m1 - M);
        float inv = 1.0f / (l0 * w0 + l1 * w1);
        float4 q0 = p4[idx0 * 32 + c4];
        float4 q1 = p4[idx1 * 32 + c4];
        res.x += (q0.x * w0 + q1.x * w1) * inv;
        res.y += (q0.y * w0 + q1.y * w1) * inv;
        res.z += (q0.z * w0 + q1.z * w1) * inv;
        res.w += (q0.w * w0 + q1.w * w1) * inv;
    }
    ((float4*)out)[i] = res;
}

extern "C" void kernel_launch(void* const* d_in, const int* in_sizes, int n_in,
                              void* d_out, int out_size, void* d_ws, size_t ws_size,
                              hipStream_t stream) {
    const float* edge_msgs   = (const float*)d_in[0];
    const float* node_states = (const float*)d_in[1];
    const float* W           = (const float*)d_in[2];
    const float* bvec        = (const float*)d_in[3];
    const int*   edges       = (const int*)d_in[4];
    float* out = (float*)d_out;

    // ws layout: pout [2][8][128][2][4][128] = 2,097,152 floats (8 MB)
    //            mlm  [2][8][128][2][4]     = 16,384 floats
    //            mll  same                   = 16,384 floats
    float* pout = (float*)d_ws;
    float* mlm  = pout + 2097152;
    float* mll  = mlm + 16384;

    edge_attn_partial<<<dim3(NB * 2 * NN), dim3(256), 0, stream>>>(
        edge_msgs, node_states, W, bvec, edges, pout, mlm, mll);
    edge_attn_combine<<<dim3(131072 / 256), dim3(256), 0, stream>>>(
        pout, mlm, mll, out);
}